// Round 1
// baseline (14010.283 us; speedup 1.0000x reference)
//
#include <hip/hip_runtime.h>
#include <hip/hip_bf16.h>

// Problem dims
#define S_LEN 256
#define EDIM  256
#define HDIM  512
#define BDIM  512
#define LOUT  8
// Scan partitioning: 8 batch-tiles x 32 h-tiles = 256 WGs (1 per CU)
#define BT    64     // batch rows per WG
#define HT    16     // h cols per WG
#define NBT   8
#define NHT   32     // WGs per batch group (barrier width)
// LDS strides (padded to break 16-way bank conflicts; keep 16B alignment)
#define WHH_STRIDE 520   // 512 + 8 bf16
#define WIH_STRIDE 264   // 256 + 8 bf16
#define GH_STRIDE  68    // 64 + 4 floats
#define HBUF (BDIM * HDIM)   // elems per h bf16 buffer

typedef short bf16x8 __attribute__((ext_vector_type(8)));
typedef float f32x4  __attribute__((ext_vector_type(4)));

__device__ __forceinline__ unsigned short f2b(float f) {
    unsigned u = __float_as_uint(f);
    u += 0x7FFFu + ((u >> 16) & 1u);   // round-to-nearest-even
    return (unsigned short)(u >> 16);
}
__device__ __forceinline__ float sigmoid_(float x) { return 1.0f / (1.0f + __expf(-x)); }
__device__ __forceinline__ float tanh_(float x)    { return 2.0f / (1.0f + __expf(-2.0f * x)) - 1.0f; }

// ---------------------------------------------------------------- cast x -> bf16
__global__ __launch_bounds__(256) void cast_f32_bf16(const float* __restrict__ in,
                                                     unsigned short* __restrict__ out,
                                                     int n4) {
    int i = blockIdx.x * blockDim.x + threadIdx.x;
    int stride = gridDim.x * blockDim.x;
    for (int idx = i; idx < n4; idx += stride) {
        float4 v = ((const float4*)in)[idx];
        ushort4 o;
        o.x = f2b(v.x); o.y = f2b(v.y); o.z = f2b(v.z); o.w = f2b(v.w);
        ((ushort4*)out)[idx] = o;
    }
}

// ---------------------------------------------------------------- persistent GRU scan
__global__ __launch_bounds__(256) void gru_scan(
    const float* __restrict__ W_ih, const float* __restrict__ W_hh,
    const float* __restrict__ b_ih, const float* __restrict__ b_hh,
    const unsigned short* __restrict__ x16,   // [B, S, E] bf16
    unsigned short* __restrict__ h16,         // 2 x [B, H] bf16 (double buffer)
    float* __restrict__ h32_out,              // [B, H] final hidden
    int* __restrict__ flags)                  // [NBT, S] arrive counters
{
    const int ht  = blockIdx.x;        // 0..31
    const int bt  = blockIdx.y;        // 0..7
    const int tid = threadIdx.x;
    const int wave = tid >> 6;
    const int lane = tid & 63;
    const int quad = lane >> 4;
    const int nl   = lane & 15;
    const int jt   = ht * HT;

    __shared__ unsigned short Whh_l[48 * WHH_STRIDE];  // rows: [r(16); z(16); n(16)] x 512
    __shared__ unsigned short Wih_l[48 * WIH_STRIDE];  // rows: [r; z; n] x 256
    __shared__ float ghb[BT * GH_STRIDE];              // cols: [r(16) z(16) nx(16) nh(16)]

    // ---- stage W_hh slice (48 rows x 512), fp32 -> bf16
    for (int f4 = tid; f4 < 48 * 128; f4 += 256) {
        int lr = f4 >> 7, c4 = f4 & 127;
        int grow = (lr >> 4) * HDIM + jt + (lr & 15);    // gate*512 + jt + i
        float4 v = ((const float4*)(W_hh + (size_t)grow * HDIM))[c4];
        ushort4 o; o.x = f2b(v.x); o.y = f2b(v.y); o.z = f2b(v.z); o.w = f2b(v.w);
        *(ushort4*)&Whh_l[lr * WHH_STRIDE + c4 * 4] = o;
    }
    // ---- stage W_ih slice (48 rows x 256)
    for (int f4 = tid; f4 < 48 * 64; f4 += 256) {
        int lr = f4 >> 6, c4 = f4 & 63;
        int grow = (lr >> 4) * HDIM + jt + (lr & 15);
        float4 v = ((const float4*)(W_ih + (size_t)grow * EDIM))[c4];
        ushort4 o; o.x = f2b(v.x); o.y = f2b(v.y); o.z = f2b(v.z); o.w = f2b(v.w);
        *(ushort4*)&Wih_l[lr * WIH_STRIDE + c4 * 4] = o;
    }
    __syncthreads();

    // per-lane A-operand pointers (m = lane&15 within wave's 16-row tile)
    const int brow = bt * BT + wave * 16 + nl;
    const unsigned short* xrow = x16 + (size_t)brow * S_LEN * EDIM + quad * 8;
    const size_t hoff = (size_t)brow * HDIM + quad * 8;

    // LDS B-fragment bases (n = lane&15)
    const int wih_b0 = (0 * 16 + nl) * WIH_STRIDE + quad * 8;
    const int wih_b1 = (1 * 16 + nl) * WIH_STRIDE + quad * 8;
    const int wih_b2 = (2 * 16 + nl) * WIH_STRIDE + quad * 8;
    const int whh_b0 = (0 * 16 + nl) * WHH_STRIDE + quad * 8;
    const int whh_b1 = (1 * 16 + nl) * WHH_STRIDE + quad * 8;
    const int whh_b2 = (2 * 16 + nl) * WHH_STRIDE + quad * 8;

    // per-thread elementwise column (fixed) + biases
    const int j = tid & 15;
    const float bir = b_ih[jt + j],           bhr = b_hh[jt + j];
    const float biz = b_ih[512 + jt + j],     bhz = b_hh[512 + jt + j];
    const float bin = b_ih[1024 + jt + j],    bhn = b_hh[1024 + jt + j];

    float hreg[4] = {0.f, 0.f, 0.f, 0.f};     // fp32 hidden state owned by this thread
    const int flg_base = bt * S_LEN;

    for (int s = 0; s < S_LEN; ++s) {
        f32x4 accr  = {0.f, 0.f, 0.f, 0.f};
        f32x4 accz  = {0.f, 0.f, 0.f, 0.f};
        f32x4 accnx = {0.f, 0.f, 0.f, 0.f};   // x-side n gate (kept separate: r scales h-side only)
        f32x4 accnh = {0.f, 0.f, 0.f, 0.f};

        // ---- x-side GEMM (independent of h: overlaps the barrier wait)
        const unsigned short* xp = xrow + (size_t)s * EDIM;
        #pragma unroll
        for (int kk = 0; kk < EDIM / 32; ++kk) {
            bf16x8 a  = *(const bf16x8*)(xp + kk * 32);
            bf16x8 br = *(const bf16x8*)&Wih_l[wih_b0 + kk * 32];
            bf16x8 bz = *(const bf16x8*)&Wih_l[wih_b1 + kk * 32];
            bf16x8 bn = *(const bf16x8*)&Wih_l[wih_b2 + kk * 32];
            accr  = __builtin_amdgcn_mfma_f32_16x16x32_bf16(a, br, accr, 0, 0, 0);
            accz  = __builtin_amdgcn_mfma_f32_16x16x32_bf16(a, bz, accz, 0, 0, 0);
            accnx = __builtin_amdgcn_mfma_f32_16x16x32_bf16(a, bn, accnx, 0, 0, 0);
        }

        // ---- wait for h[s] (written by this bt-group at step s-1)
        if (s > 0) {
            if (tid == 0) {
                while (__hip_atomic_load(&flags[flg_base + s - 1], __ATOMIC_ACQUIRE,
                                         __HIP_MEMORY_SCOPE_AGENT) < NHT) {
                    __builtin_amdgcn_s_sleep(1);
                }
            }
            __syncthreads();
            __threadfence();   // acquire side: invalidate stale L1/L2 before reading h16
        }

        // ---- h-side GEMM
        const unsigned short* hp = h16 + (size_t)(s & 1) * HBUF + hoff;
        #pragma unroll
        for (int kk = 0; kk < HDIM / 32; ++kk) {
            bf16x8 a  = *(const bf16x8*)(hp + kk * 32);
            bf16x8 br = *(const bf16x8*)&Whh_l[whh_b0 + kk * 32];
            bf16x8 bz = *(const bf16x8*)&Whh_l[whh_b1 + kk * 32];
            bf16x8 bn = *(const bf16x8*)&Whh_l[whh_b2 + kk * 32];
            accr  = __builtin_amdgcn_mfma_f32_16x16x32_bf16(a, br, accr, 0, 0, 0);
            accz  = __builtin_amdgcn_mfma_f32_16x16x32_bf16(a, bz, accz, 0, 0, 0);
            accnh = __builtin_amdgcn_mfma_f32_16x16x32_bf16(a, bn, accnh, 0, 0, 0);
        }

        // ---- spill gate pre-activations to LDS (C layout: row = quad*4+reg, col = nl)
        {
            const int mr = (wave * 16 + quad * 4) * GH_STRIDE;
            #pragma unroll
            for (int r = 0; r < 4; ++r) {
                ghb[mr + r * GH_STRIDE +  0 + nl] = accr[r];
                ghb[mr + r * GH_STRIDE + 16 + nl] = accz[r];
                ghb[mr + r * GH_STRIDE + 32 + nl] = accnx[r];
                ghb[mr + r * GH_STRIDE + 48 + nl] = accnh[r];
            }
        }
        __syncthreads();

        // ---- elementwise gate math in fp32; h carried in registers
        unsigned short* hwr = h16 + (size_t)((s + 1) & 1) * HBUF;
        #pragma unroll
        for (int it = 0; it < 4; ++it) {
            int bl = (tid >> 4) + it * 16;
            float gr  = ghb[bl * GH_STRIDE + j];
            float gz  = ghb[bl * GH_STRIDE + 16 + j];
            float gnx = ghb[bl * GH_STRIDE + 32 + j];
            float gnh = ghb[bl * GH_STRIDE + 48 + j];
            float rr = sigmoid_(gr + bir + bhr);
            float zz = sigmoid_(gz + biz + bhz);
            float nn = tanh_(gnx + bin + rr * (gnh + bhn));
            float hn = (1.0f - zz) * nn + zz * hreg[it];
            hreg[it] = hn;
            hwr[(size_t)(bt * BT + bl) * HDIM + jt + j] = f2b(hn);
        }
        __threadfence();     // release side: drain h16 stores device-wide
        __syncthreads();
        if (tid == 0) {
            __hip_atomic_fetch_add(&flags[flg_base + s], 1, __ATOMIC_RELEASE,
                                   __HIP_MEMORY_SCOPE_AGENT);
        }
    }

    // ---- final hidden state to fp32 global for the head
    #pragma unroll
    for (int it = 0; it < 4; ++it) {
        int bl = (tid >> 4) + it * 16;
        h32_out[(size_t)(bt * BT + bl) * HDIM + jt + j] = hreg[it];
    }
}

// ---------------------------------------------------------------- head: logits + softmax
__global__ __launch_bounds__(256) void out_head(const float* __restrict__ h32,
                                                const float* __restrict__ W_out,
                                                const float* __restrict__ b_out,
                                                float* __restrict__ out) {
    int b = blockIdx.x * blockDim.x + threadIdx.x;   // 0..511
    if (b >= BDIM) return;
    float acc[LOUT];
    #pragma unroll
    for (int l = 0; l < LOUT; ++l) acc[l] = b_out[l];
    const float4* hrow = (const float4*)(h32 + (size_t)b * HDIM);
    for (int k4 = 0; k4 < HDIM / 4; ++k4) {
        float4 hv = hrow[k4];
        #pragma unroll
        for (int l = 0; l < LOUT; ++l) {
            const float4 wv = ((const float4*)(W_out + l * HDIM))[k4];
            acc[l] += hv.x * wv.x + hv.y * wv.y + hv.z * wv.z + hv.w * wv.w;
        }
    }
    float m = acc[0];
    #pragma unroll
    for (int l = 1; l < LOUT; ++l) m = fmaxf(m, acc[l]);
    float sum = 0.f;
    #pragma unroll
    for (int l = 0; l < LOUT; ++l) { acc[l] = __expf(acc[l] - m); sum += acc[l]; }
    float inv = 1.0f / sum;
    float4 o0 = {acc[0] * inv, acc[1] * inv, acc[2] * inv, acc[3] * inv};
    float4 o1 = {acc[4] * inv, acc[5] * inv, acc[6] * inv, acc[7] * inv};
    ((float4*)(out + (size_t)b * LOUT))[0] = o0;
    ((float4*)(out + (size_t)b * LOUT))[1] = o1;
}

// ---------------------------------------------------------------- launch
extern "C" void kernel_launch(void* const* d_in, const int* in_sizes, int n_in,
                              void* d_out, int out_size, void* d_ws, size_t ws_size,
                              hipStream_t stream) {
    const float* x     = (const float*)d_in[0];
    const float* W_ih  = (const float*)d_in[1];
    const float* W_hh  = (const float*)d_in[2];
    const float* b_ih  = (const float*)d_in[3];
    const float* b_hh  = (const float*)d_in[4];
    const float* W_out = (const float*)d_in[5];
    const float* b_out = (const float*)d_in[6];
    float* out = (float*)d_out;

    char* w = (char*)d_ws;
    unsigned short* x16 = (unsigned short*)w;  w += (size_t)BDIM * S_LEN * EDIM * 2;  // 67 MB
    unsigned short* h16 = (unsigned short*)w;  w += (size_t)2 * HBUF * 2;             // 1 MB
    float* h32          = (float*)w;           w += (size_t)BDIM * HDIM * 4;          // 1 MB
    int* flags          = (int*)w;             w += (size_t)NBT * S_LEN * 4;          // 8 KB

    hipMemsetAsync(flags, 0, NBT * S_LEN * sizeof(int), stream);
    hipMemsetAsync(h16, 0, HBUF * sizeof(unsigned short), stream);  // h[0] = 0

    const int n4 = (BDIM * S_LEN * EDIM) / 4;
    cast_f32_bf16<<<8192, 256, 0, stream>>>(x, x16, n4);

    gru_scan<<<dim3(NHT, NBT), 256, 0, stream>>>(W_ih, W_hh, b_ih, b_hh,
                                                 x16, h16, h32, flags);

    out_head<<<2, 256, 0, stream>>>(h32, W_out, b_out, out);
}

// Round 3
// 1889.940 us; speedup vs baseline: 7.4131x; 7.4131x over previous
//
#include <hip/hip_runtime.h>
#include <hip/hip_bf16.h>

// Problem dims
#define S_LEN 256
#define EDIM  256
#define HDIM  512
#define BDIM  512
#define LOUT  8
// Scan partitioning: 8 batch-tiles x 16 h-tiles = 128 WGs (1 per CU, all co-resident)
#define BT    64     // batch rows per WG
#define HT    32     // h cols per WG
#define NBT   8
#define NHT   16     // WGs per batch group (barrier width)
// LDS strides (bf16 elems). 520*2B=1040B row stride -> start bank 4r%32 -> 2-way (free).
#define WHH_STRIDE 520
#define WIH_STRIDE 264
#define HST_STRIDE 40    // h staging, ushort elems (80B rows)
#define HBUF (BDIM * HDIM)   // elems per h bf16 buffer

typedef short bf16x8 __attribute__((ext_vector_type(8)));
typedef float f32x4  __attribute__((ext_vector_type(4)));
typedef unsigned int u32x4 __attribute__((ext_vector_type(4)));

__device__ __forceinline__ unsigned short f2b(float f) {
    unsigned u = __float_as_uint(f);
    u += 0x7FFFu + ((u >> 16) & 1u);   // round-to-nearest-even
    return (unsigned short)(u >> 16);
}
__device__ __forceinline__ float sigmoid_(float x) { return 1.0f / (1.0f + __expf(-x)); }
__device__ __forceinline__ float tanh_(float x)    { return 2.0f / (1.0f + __expf(-2.0f * x)) - 1.0f; }

// Coherent (device-scope, cache-bypass) 16B accesses via ext-vector operands
// (plain uint4 is a struct -> "indirect register inputs" asm error).
// sc0 sc1 => coherent point (memory-side cache) -- no L2 wb/inv storms.
__device__ __forceinline__ void gst_b128_sys(u32x4 v, void* addr) {
    asm volatile("global_store_dwordx4 %0, %1, off sc0 sc1" :: "v"(addr), "v"(v) : "memory");
}
__device__ __forceinline__ u32x4 gld_b128_sys(const void* addr) {
    u32x4 v;
    asm volatile("global_load_dwordx4 %0, %1, off sc0 sc1" : "=v"(v) : "v"(addr) : "memory");
    return v;
}
__device__ __forceinline__ void wait_vm0() {
    asm volatile("s_waitcnt vmcnt(0)" ::: "memory");
}

// ---------------------------------------------------------------- cast x -> bf16
__global__ __launch_bounds__(256) void cast_f32_bf16(const float* __restrict__ in,
                                                     unsigned short* __restrict__ out,
                                                     int n4) {
    int i = blockIdx.x * blockDim.x + threadIdx.x;
    int stride = gridDim.x * blockDim.x;
    for (int idx = i; idx < n4; idx += stride) {
        float4 v = ((const float4*)in)[idx];
        ushort4 o;
        o.x = f2b(v.x); o.y = f2b(v.y); o.z = f2b(v.z); o.w = f2b(v.w);
        ((ushort4*)out)[idx] = o;
    }
}

// ---------------------------------------------------------------- persistent GRU scan
__global__ __launch_bounds__(256) void gru_scan(
    const float* __restrict__ W_ih, const float* __restrict__ W_hh,
    const float* __restrict__ b_ih, const float* __restrict__ b_hh,
    const unsigned short* __restrict__ x16,   // [B, S, E] bf16
    unsigned short* __restrict__ h16,         // 2 x [B, H] bf16 (double buffer)
    float* __restrict__ h32_out,              // [B, H] final hidden
    int* __restrict__ flags)                  // [NBT, S] arrive counters
{
    const int ht  = blockIdx.x;        // 0..15
    const int bt  = blockIdx.y;        // 0..7
    const int tid = threadIdx.x;
    const int wave = tid >> 6;
    const int lane = tid & 63;
    const int quad = lane >> 4;
    const int nl   = lane & 15;
    const int jt   = ht * HT;

    __shared__ unsigned short Whh_l[96 * WHH_STRIDE];  // [gate(3) x 32 cols] x 512 k
    __shared__ unsigned short Wih_l[96 * WIH_STRIDE];  // [gate(3) x 32 cols] x 256 k
    __shared__ unsigned short hstage[BT * HST_STRIDE]; // pack C-layout -> row-major 16B chunks

    // ---- stage W_hh slice (96 rows x 512), fp32 -> bf16
    for (int f4 = tid; f4 < 96 * 128; f4 += 256) {
        int lr = f4 >> 7, c4 = f4 & 127;
        int grow = (lr >> 5) * HDIM + jt + (lr & 31);    // gate*512 + jt + c
        float4 v = ((const float4*)(W_hh + (size_t)grow * HDIM))[c4];
        ushort4 o; o.x = f2b(v.x); o.y = f2b(v.y); o.z = f2b(v.z); o.w = f2b(v.w);
        *(ushort4*)&Whh_l[lr * WHH_STRIDE + c4 * 4] = o;
    }
    // ---- stage W_ih slice (96 rows x 256)
    for (int f4 = tid; f4 < 96 * 64; f4 += 256) {
        int lr = f4 >> 6, c4 = f4 & 63;
        int grow = (lr >> 5) * HDIM + jt + (lr & 31);
        float4 v = ((const float4*)(W_ih + (size_t)grow * EDIM))[c4];
        ushort4 o; o.x = f2b(v.x); o.y = f2b(v.y); o.z = f2b(v.z); o.w = f2b(v.w);
        *(ushort4*)&Wih_l[lr * WIH_STRIDE + c4 * 4] = o;
    }
    __syncthreads();

    // A-operand pointers (m = lane&15 within wave's 16-row batch tile)
    const int brow = bt * BT + wave * 16 + nl;
    const unsigned short* xrow = x16 + (size_t)brow * S_LEN * EDIM + quad * 8;
    const size_t hoff = (size_t)brow * HDIM + quad * 8;

    // LDS B-fragment bases: row = gate*32 + t*16 + nl
    int wih_b[3][2], whh_b[3][2];
    #pragma unroll
    for (int g = 0; g < 3; ++g)
        #pragma unroll
        for (int t = 0; t < 2; ++t) {
            wih_b[g][t] = (g * 32 + t * 16 + nl) * WIH_STRIDE + quad * 8;
            whh_b[g][t] = (g * 32 + t * 16 + nl) * WHH_STRIDE + quad * 8;
        }

    // per-thread output columns (C layout: col = t*16 + nl) + biases
    const int jc0 = jt + nl, jc1 = jt + 16 + nl;
    const float bir[2] = {b_ih[jc0],        b_ih[jc1]};
    const float bhr[2] = {b_hh[jc0],        b_hh[jc1]};
    const float biz[2] = {b_ih[512 + jc0],  b_ih[512 + jc1]};
    const float bhz[2] = {b_hh[512 + jc0],  b_hh[512 + jc1]};
    const float bin[2] = {b_ih[1024 + jc0], b_ih[1024 + jc1]};
    const float bhn[2] = {b_hh[1024 + jc0], b_hh[1024 + jc1]};

    float hreg[2][4] = {{0.f,0.f,0.f,0.f},{0.f,0.f,0.f,0.f}};  // h carried in C layout
    const int flg_base = bt * S_LEN;

    // preload x A-fragments for step 0
    bf16x8 xf[8];
    #pragma unroll
    for (int kk = 0; kk < 8; ++kk) xf[kk] = *(const bf16x8*)(xrow + kk * 32);

    for (int s = 0; s < S_LEN; ++s) {
        f32x4 ar[2], az[2], anx[2], anh[2];
        #pragma unroll
        for (int t = 0; t < 2; ++t) {
            ar[t] = (f32x4){0.f,0.f,0.f,0.f};  az[t]  = (f32x4){0.f,0.f,0.f,0.f};
            anx[t] = (f32x4){0.f,0.f,0.f,0.f}; anh[t] = (f32x4){0.f,0.f,0.f,0.f};
        }

        // ---- x-side GEMM for step s (overlaps producers of h[s-1] finishing)
        #pragma unroll
        for (int kk = 0; kk < 8; ++kk) {
            bf16x8 a = xf[kk];
            #pragma unroll
            for (int t = 0; t < 2; ++t) {
                ar[t]  = __builtin_amdgcn_mfma_f32_16x16x32_bf16(a, *(const bf16x8*)&Wih_l[wih_b[0][t] + kk * 32], ar[t],  0, 0, 0);
                az[t]  = __builtin_amdgcn_mfma_f32_16x16x32_bf16(a, *(const bf16x8*)&Wih_l[wih_b[1][t] + kk * 32], az[t],  0, 0, 0);
                anx[t] = __builtin_amdgcn_mfma_f32_16x16x32_bf16(a, *(const bf16x8*)&Wih_l[wih_b[2][t] + kk * 32], anx[t], 0, 0, 0);
            }
        }

        // ---- wait for h[s] complete (written by this bt-group at step s-1)
        if (s > 0) {
            if (tid == 0) {
                while (__hip_atomic_load(&flags[flg_base + s - 1], __ATOMIC_RELAXED,
                                         __HIP_MEMORY_SCOPE_AGENT) < NHT) {
                    __builtin_amdgcn_s_sleep(2);
                }
            }
            __syncthreads();   // no cache maintenance: data read via coherent loads below
        }

        // ---- coherent A-fragment loads of h[s] (bypass stale L1/L2)
        const unsigned short* hp = h16 + (size_t)(s & 1) * HBUF + hoff;
        u32x4 ha[16];
        #pragma unroll
        for (int kk = 0; kk < 16; ++kk) ha[kk] = gld_b128_sys(hp + kk * 32);
        wait_vm0();

        // ---- prefetch next step's x A-fragments (overlaps h-GEMM)
        if (s + 1 < S_LEN) {
            const unsigned short* xp = xrow + (size_t)(s + 1) * EDIM;
            #pragma unroll
            for (int kk = 0; kk < 8; ++kk) xf[kk] = *(const bf16x8*)(xp + kk * 32);
        }

        // ---- h-side GEMM
        #pragma unroll
        for (int kk = 0; kk < 16; ++kk) {
            union { u32x4 u; bf16x8 b; } cv; cv.u = ha[kk];
            bf16x8 a = cv.b;
            #pragma unroll
            for (int t = 0; t < 2; ++t) {
                ar[t]  = __builtin_amdgcn_mfma_f32_16x16x32_bf16(a, *(const bf16x8*)&Whh_l[whh_b[0][t] + kk * 32], ar[t],  0, 0, 0);
                az[t]  = __builtin_amdgcn_mfma_f32_16x16x32_bf16(a, *(const bf16x8*)&Whh_l[whh_b[1][t] + kk * 32], az[t],  0, 0, 0);
                anh[t] = __builtin_amdgcn_mfma_f32_16x16x32_bf16(a, *(const bf16x8*)&Whh_l[whh_b[2][t] + kk * 32], anh[t], 0, 0, 0);
            }
        }

        // ---- gate math fully in C-layout registers (row = quad*4+r, col = t*16+nl)
        #pragma unroll
        for (int t = 0; t < 2; ++t) {
            #pragma unroll
            for (int r = 0; r < 4; ++r) {
                float rr = sigmoid_(ar[t][r] + bir[t] + bhr[t]);
                float zz = sigmoid_(az[t][r] + biz[t] + bhz[t]);
                float nn = tanh_(anx[t][r] + bin[t] + rr * (anh[t][r] + bhn[t]));
                float hn = (1.0f - zz) * nn + zz * hreg[t][r];
                hreg[t][r] = hn;
                hstage[(wave * 16 + quad * 4 + r) * HST_STRIDE + t * 16 + nl] = f2b(hn);
            }
        }
        __syncthreads();

        // ---- pack to 16B chunks and store write-through (coherent)
        {
            int row = tid >> 2, ch = tid & 3;
            u32x4 v = *(const u32x4*)&hstage[row * HST_STRIDE + ch * 8];
            unsigned short* dst = h16 + (size_t)((s + 1) & 1) * HBUF
                                + (size_t)(bt * BT + row) * HDIM + jt + ch * 8;
            gst_b128_sys(v, dst);
        }
        wait_vm0();        // drain this thread's coherent store
        __syncthreads();   // all threads' stores globally visible
        if (tid == 0) {
            __hip_atomic_fetch_add(&flags[flg_base + s], 1, __ATOMIC_RELAXED,
                                   __HIP_MEMORY_SCOPE_AGENT);
        }
    }

    // ---- final hidden state to fp32 global for the head
    #pragma unroll
    for (int t = 0; t < 2; ++t)
        #pragma unroll
        for (int r = 0; r < 4; ++r)
            h32_out[(size_t)(bt * BT + wave * 16 + quad * 4 + r) * HDIM + jt + t * 16 + nl] = hreg[t][r];
}

// ---------------------------------------------------------------- head: logits + softmax
__global__ __launch_bounds__(256) void out_head(const float* __restrict__ h32,
                                                const float* __restrict__ W_out,
                                                const float* __restrict__ b_out,
                                                float* __restrict__ out) {
    int b = blockIdx.x * blockDim.x + threadIdx.x;   // 0..511
    if (b >= BDIM) return;
    float acc[LOUT];
    #pragma unroll
    for (int l = 0; l < LOUT; ++l) acc[l] = b_out[l];
    const float4* hrow = (const float4*)(h32 + (size_t)b * HDIM);
    for (int k4 = 0; k4 < HDIM / 4; ++k4) {
        float4 hv = hrow[k4];
        #pragma unroll
        for (int l = 0; l < LOUT; ++l) {
            const float4 wv = ((const float4*)(W_out + l * HDIM))[k4];
            acc[l] += hv.x * wv.x + hv.y * wv.y + hv.z * wv.z + hv.w * wv.w;
        }
    }
    float m = acc[0];
    #pragma unroll
    for (int l = 1; l < LOUT; ++l) m = fmaxf(m, acc[l]);
    float sum = 0.f;
    #pragma unroll
    for (int l = 0; l < LOUT; ++l) { acc[l] = __expf(acc[l] - m); sum += acc[l]; }
    float inv = 1.0f / sum;
    float4 o0 = {acc[0] * inv, acc[1] * inv, acc[2] * inv, acc[3] * inv};
    float4 o1 = {acc[4] * inv, acc[5] * inv, acc[6] * inv, acc[7] * inv};
    ((float4*)(out + (size_t)b * LOUT))[0] = o0;
    ((float4*)(out + (size_t)b * LOUT))[1] = o1;
}

// ---------------------------------------------------------------- launch
extern "C" void kernel_launch(void* const* d_in, const int* in_sizes, int n_in,
                              void* d_out, int out_size, void* d_ws, size_t ws_size,
                              hipStream_t stream) {
    const float* x     = (const float*)d_in[0];
    const float* W_ih  = (const float*)d_in[1];
    const float* W_hh  = (const float*)d_in[2];
    const float* b_ih  = (const float*)d_in[3];
    const float* b_hh  = (const float*)d_in[4];
    const float* W_out = (const float*)d_in[5];
    const float* b_out = (const float*)d_in[6];
    float* out = (float*)d_out;

    char* w = (char*)d_ws;
    unsigned short* x16 = (unsigned short*)w;  w += (size_t)BDIM * S_LEN * EDIM * 2;  // 67 MB
    unsigned short* h16 = (unsigned short*)w;  w += (size_t)2 * HBUF * 2;             // 1 MB
    float* h32          = (float*)w;           w += (size_t)BDIM * HDIM * 4;          // 1 MB
    int* flags          = (int*)w;             w += (size_t)NBT * S_LEN * 4;          // 8 KB

    (void)hipMemsetAsync(flags, 0, NBT * S_LEN * sizeof(int), stream);
    (void)hipMemsetAsync(h16, 0, HBUF * sizeof(unsigned short), stream);  // h[0] = 0

    const int n4 = (BDIM * S_LEN * EDIM) / 4;
    cast_f32_bf16<<<8192, 256, 0, stream>>>(x, x16, n4);

    gru_scan<<<dim3(NHT, NBT), 256, 0, stream>>>(W_ih, W_hh, b_ih, b_hh,
                                                 x16, h16, h32, flags);

    out_head<<<2, 256, 0, stream>>>(h32, W_out, b_out, out);
}